// Round 1
// baseline (845.494 us; speedup 1.0000x reference)
//
#include <hip/hip_runtime.h>
#include <cstdint>
#include <cstddef>

#define NN 8192
#define DIN 256
#define DHID 128
#define DOUT 64
#define MAXDEG 256

using short8  = __attribute__((ext_vector_type(8))) short;
using floatx4 = __attribute__((ext_vector_type(4))) float;

__device__ inline unsigned short f2bf(float x) {
  union { float f; unsigned u; } c; c.f = x;
  unsigned r = (c.u + 0x7FFFu + ((c.u >> 16) & 1u)) >> 16;   // RNE
  return (unsigned short)r;
}

// ---------------- GEMM1: Wh1 = feat[8192,256] @ W1[256,128] (fp32) ----------
__global__ __launch_bounds__(256) void k_gemm1(const float* __restrict__ feat,
                                               const float* __restrict__ W1,
                                               float* __restrict__ Wh1) {
  __shared__ float Ws[64 * DHID];     // k-chunk x 128 cols (32 KB)
  __shared__ float Fs[64][65];        // 64 rows x 64 k (stride 65: conflict-free)
  const int tid = threadIdx.x;
  const int cx = tid & 31;            // cols cx*4..cx*4+3
  const int ry = tid >> 5;            // rows ry*8..ry*8+7
  const int r0 = blockIdx.x * 64;
  float acc[8][4] = {};
  for (int kc = 0; kc < DIN; kc += 64) {
    const float4* src = (const float4*)(W1 + (size_t)kc * DHID);
    float4* dst = (float4*)Ws;
    #pragma unroll
    for (int i = 0; i < 8; ++i) dst[i * 256 + tid] = src[i * 256 + tid];
    #pragma unroll
    for (int i = 0; i < 4; ++i) {
      int idx = i * 256 + tid;
      int row = idx >> 4, kq = idx & 15;
      float4 v = *(const float4*)(feat + (size_t)(r0 + row) * DIN + kc + kq * 4);
      Fs[row][kq * 4 + 0] = v.x; Fs[row][kq * 4 + 1] = v.y;
      Fs[row][kq * 4 + 2] = v.z; Fs[row][kq * 4 + 3] = v.w;
    }
    __syncthreads();
    #pragma unroll 4
    for (int k = 0; k < 64; ++k) {
      float4 w = *(const float4*)(Ws + k * DHID + cx * 4);
      #pragma unroll
      for (int r = 0; r < 8; ++r) {
        float f = Fs[ry * 8 + r][k];
        acc[r][0] += f * w.x; acc[r][1] += f * w.y;
        acc[r][2] += f * w.z; acc[r][3] += f * w.w;
      }
    }
    __syncthreads();
  }
  #pragma unroll
  for (int r = 0; r < 8; ++r) {
    float4 o = make_float4(acc[r][0], acc[r][1], acc[r][2], acc[r][3]);
    *(float4*)(Wh1 + (size_t)(r0 + ry * 8 + r) * DHID + cx * 4) = o;
  }
}

// ---------------- GEMM2: Wh2 = h1[8192,128] @ W2[128,64] (fp32) -------------
__global__ __launch_bounds__(256) void k_gemm2(const float* __restrict__ h1,
                                               const float* __restrict__ W2,
                                               float* __restrict__ Wh2) {
  __shared__ float Ws[64 * DOUT];     // 16 KB
  __shared__ float Fs[128][65];       // 33 KB
  const int tid = threadIdx.x;
  const int cx = tid & 15;            // cols cx*4
  const int ry = tid >> 4;            // rows ry*8 (0..15 -> 128 rows)
  const int r0 = blockIdx.x * 128;
  float acc[8][4] = {};
  for (int kc = 0; kc < DHID; kc += 64) {
    const float4* src = (const float4*)(W2 + (size_t)kc * DOUT);
    float4* dst = (float4*)Ws;
    #pragma unroll
    for (int i = 0; i < 4; ++i) dst[i * 256 + tid] = src[i * 256 + tid];
    #pragma unroll
    for (int i = 0; i < 8; ++i) {
      int idx = i * 256 + tid;
      int row = idx >> 4, kq = idx & 15;
      float4 v = *(const float4*)(h1 + (size_t)(r0 + row) * DHID + kc + kq * 4);
      Fs[row][kq * 4 + 0] = v.x; Fs[row][kq * 4 + 1] = v.y;
      Fs[row][kq * 4 + 2] = v.z; Fs[row][kq * 4 + 3] = v.w;
    }
    __syncthreads();
    #pragma unroll 4
    for (int k = 0; k < 64; ++k) {
      float4 w = *(const float4*)(Ws + k * DOUT + cx * 4);
      #pragma unroll
      for (int r = 0; r < 8; ++r) {
        float f = Fs[ry * 8 + r][k];
        acc[r][0] += f * w.x; acc[r][1] += f * w.y;
        acc[r][2] += f * w.z; acc[r][3] += f * w.w;
      }
    }
    __syncthreads();
  }
  #pragma unroll
  for (int r = 0; r < 8; ++r) {
    float4 o = make_float4(acc[r][0], acc[r][1], acc[r][2], acc[r][3]);
    *(float4*)(Wh2 + (size_t)(r0 + ry * 8 + r) * DOUT + cx * 4) = o;
  }
}

// ---------------- f1/f2 vectors: layer 1 (128-dim dot with a halves) --------
__global__ __launch_bounds__(256) void k_fvec1(const float* __restrict__ Wh1,
                                               const float* __restrict__ a1,
                                               float* __restrict__ f1, float* __restrict__ f2) {
  int wv = threadIdx.x >> 6, lane = threadIdx.x & 63;
  int row = blockIdx.x * 4 + wv;
  float2 x = *(const float2*)(Wh1 + (size_t)row * DHID + lane * 2);
  float2 u = *(const float2*)(a1 + lane * 2);
  float2 v = *(const float2*)(a1 + DHID + lane * 2);
  float s1 = x.x * u.x + x.y * u.y;
  float s2 = x.x * v.x + x.y * v.y;
  #pragma unroll
  for (int off = 32; off; off >>= 1) { s1 += __shfl_down(s1, off); s2 += __shfl_down(s2, off); }
  if (lane == 0) { f1[row] = s1; f2[row] = s2; }
}

__global__ __launch_bounds__(256) void k_fvec2(const float* __restrict__ Wh2,
                                               const float* __restrict__ a2,
                                               float* __restrict__ f1, float* __restrict__ f2) {
  int wv = threadIdx.x >> 6, lane = threadIdx.x & 63;
  int row = blockIdx.x * 4 + wv;
  float x = Wh2[(size_t)row * DOUT + lane];
  float s1 = x * a2[lane];
  float s2 = x * a2[DOUT + lane];
  #pragma unroll
  for (int off = 32; off; off >>= 1) { s1 += __shfl_down(s1, off); s2 += __shfl_down(s2, off); }
  if (lane == 0) { f1[row] = s1; f2[row] = s2; }
}

// ---------------- Layer-1 attention: scan adj, CSR, softmax, dense att, SpMM, ELU
__global__ __launch_bounds__(256) void k_att1(const float* __restrict__ adj,
                                              const float* __restrict__ f1,
                                              const float* __restrict__ f2,
                                              const float* __restrict__ Wh1,
                                              float* __restrict__ att_out,
                                              float* __restrict__ h1,
                                              int* __restrict__ csr,
                                              int* __restrict__ degree) {
  __shared__ int   scols[MAXDEG];
  __shared__ float sval[MAXDEG];
  __shared__ float red[256];
  __shared__ int   cnt;
  const int tid = threadIdx.x;
  const int row = blockIdx.x;
  if (tid == 0) cnt = 0;
  __syncthreads();
  // Phase A: scan adjacency row, collect neighbor columns
  const float4* arow = (const float4*)(adj + (size_t)row * NN);
  #pragma unroll
  for (int it = 0; it < 8; ++it) {
    int idx = it * 256 + tid;
    float4 v = arow[idx];
    if (v.x > 0.0f) { int s = atomicAdd(&cnt, 1); if (s < MAXDEG) scols[s] = idx * 4 + 0; }
    if (v.y > 0.0f) { int s = atomicAdd(&cnt, 1); if (s < MAXDEG) scols[s] = idx * 4 + 1; }
    if (v.z > 0.0f) { int s = atomicAdd(&cnt, 1); if (s < MAXDEG) scols[s] = idx * 4 + 2; }
    if (v.w > 0.0f) { int s = atomicAdd(&cnt, 1); if (s < MAXDEG) scols[s] = idx * 4 + 3; }
  }
  __syncthreads();
  const int deg = min(cnt, MAXDEG);
  if (tid == 0) degree[row] = deg;
  for (int t = tid; t < deg; t += 256) csr[(size_t)row * MAXDEG + t] = scols[t];
  // Phase B: e = leakyrelu(f1[row] + f2[col]); softmax over neighbors
  const float base = f1[row];
  float lmax = -3.0e38f;
  for (int t = tid; t < deg; t += 256) {
    float e = base + f2[scols[t]];
    e = e > 0.0f ? e : 0.2f * e;
    sval[t] = e;
    lmax = fmaxf(lmax, e);
  }
  red[tid] = lmax; __syncthreads();
  #pragma unroll
  for (int off = 128; off; off >>= 1) { if (tid < off) red[tid] = fmaxf(red[tid], red[tid + off]); __syncthreads(); }
  const float m = red[0];
  __syncthreads();
  float lsum = 0.0f;
  for (int t = tid; t < deg; t += 256) { float ex = expf(sval[t] - m); sval[t] = ex; lsum += ex; }
  red[tid] = lsum; __syncthreads();
  #pragma unroll
  for (int off = 128; off; off >>= 1) { if (tid < off) red[tid] += red[tid + off]; __syncthreads(); }
  const float inv = 1.0f / red[0];
  __syncthreads();
  for (int t = tid; t < deg; t += 256) sval[t] *= inv;
  // Phase C: dense attention row (zeros, or uniform 1/N if isolated row)
  const float fill = (deg == 0) ? (1.0f / (float)NN) : 0.0f;
  float4 fv = make_float4(fill, fill, fill, fill);
  float4* orow = (float4*)(att_out + (size_t)row * NN);
  #pragma unroll
  for (int it = 0; it < 8; ++it) orow[it * 256 + tid] = fv;
  __syncthreads();
  // Phase D: scatter softmax values
  for (int t = tid; t < deg; t += 256) att_out[(size_t)row * NN + scols[t]] = sval[t];
  // Phase E: hp = att_row @ Wh1 (sparse), ELU -> h1
  const int d = tid & 127, g = tid >> 7;
  float acc = 0.0f;
  if (deg > 0) {
    for (int t = g; t < deg; t += 2) acc += sval[t] * Wh1[(size_t)scols[t] * DHID + d];
  } else {
    for (int r = g; r < NN; r += 2) acc += Wh1[(size_t)r * DHID + d];
    acc *= (1.0f / (float)NN);
  }
  __syncthreads();
  red[tid] = acc; __syncthreads();
  if (tid < 128) {
    float h = red[tid] + red[tid + 128];
    h = h > 0.0f ? h : (expf(h) - 1.0f);
    h1[(size_t)row * DHID + tid] = h;
  }
}

// ---------------- Layer-2 attention: reuse CSR, no adj re-read -> h2 --------
__global__ __launch_bounds__(256) void k_att2(const int* __restrict__ csr,
                                              const int* __restrict__ degree,
                                              const float* __restrict__ f1,
                                              const float* __restrict__ f2,
                                              const float* __restrict__ Wh2,
                                              float* __restrict__ h2) {
  __shared__ int   scols[MAXDEG];
  __shared__ float sval[MAXDEG];
  __shared__ float red[256];
  const int tid = threadIdx.x;
  const int row = blockIdx.x;
  const int deg = degree[row];
  for (int t = tid; t < deg; t += 256) scols[t] = csr[(size_t)row * MAXDEG + t];
  __syncthreads();
  const float base = f1[row];
  float lmax = -3.0e38f;
  for (int t = tid; t < deg; t += 256) {
    float e = base + f2[scols[t]];
    e = e > 0.0f ? e : 0.2f * e;
    sval[t] = e;
    lmax = fmaxf(lmax, e);
  }
  red[tid] = lmax; __syncthreads();
  #pragma unroll
  for (int off = 128; off; off >>= 1) { if (tid < off) red[tid] = fmaxf(red[tid], red[tid + off]); __syncthreads(); }
  const float m = red[0];
  __syncthreads();
  float lsum = 0.0f;
  for (int t = tid; t < deg; t += 256) { float ex = expf(sval[t] - m); sval[t] = ex; lsum += ex; }
  red[tid] = lsum; __syncthreads();
  #pragma unroll
  for (int off = 128; off; off >>= 1) { if (tid < off) red[tid] += red[tid + off]; __syncthreads(); }
  const float inv = 1.0f / red[0];
  __syncthreads();
  for (int t = tid; t < deg; t += 256) sval[t] *= inv;
  __syncthreads();
  const int d = tid & 63, g = tid >> 6;
  float acc = 0.0f;
  if (deg > 0) {
    for (int t = g; t < deg; t += 4) acc += sval[t] * Wh2[(size_t)scols[t] * DOUT + d];
  } else {
    for (int r = g; r < NN; r += 4) acc += Wh2[(size_t)r * DOUT + d];
    acc *= (1.0f / (float)NN);
  }
  red[tid] = acc; __syncthreads();
  if (tid < 64) h2[(size_t)row * DOUT + tid] = red[tid] + red[tid + 64] + red[tid + 128] + red[tid + 192];
}

// ---------------- genenet: sigmoid(h2 @ h2^T) * rowmask  (bf16 MFMA) --------
__global__ __launch_bounds__(256) void k_genenet(const float* __restrict__ h2,
                                                 const int* __restrict__ degree,
                                                 float* __restrict__ out) {
  __shared__ unsigned short As[128 * 72];   // rows R0.., stride 72 bf16 (pad)
  __shared__ unsigned short Bs[128 * 72];   // rows C0..
  __shared__ float dmask[128];
  const int tid = threadIdx.x;
  const int R0 = blockIdx.x * 128, C0 = blockIdx.y * 128;
  #pragma unroll
  for (int it = 0; it < 8; ++it) {
    int idx = it * 256 + tid;
    int r = idx >> 4, kq = idx & 15;
    float4 va = *(const float4*)(h2 + (size_t)(R0 + r) * DOUT + kq * 4);
    float4 vb = *(const float4*)(h2 + (size_t)(C0 + r) * DOUT + kq * 4);
    ushort4 ba, bb;
    ba.x = f2bf(va.x); ba.y = f2bf(va.y); ba.z = f2bf(va.z); ba.w = f2bf(va.w);
    bb.x = f2bf(vb.x); bb.y = f2bf(vb.y); bb.z = f2bf(vb.z); bb.w = f2bf(vb.w);
    *(ushort4*)&As[r * 72 + kq * 4] = ba;
    *(ushort4*)&Bs[r * 72 + kq * 4] = bb;
  }
  if (tid < 128) dmask[tid] = (degree[R0 + tid] > 0) ? 1.0f : 0.0f;
  __syncthreads();
  const int wave = tid >> 6, lane = tid & 63;
  const int wr = wave >> 1, wc = wave & 1;     // 2x2 waves over 128x128 tile
  const int lr = lane & 15, quad = lane >> 4;
  short8 a[4][2], b[4][2];
  #pragma unroll
  for (int mi = 0; mi < 4; ++mi) {
    int r = wr * 64 + mi * 16 + lr;
    a[mi][0] = *(const short8*)(const void*)&As[r * 72 + quad * 8];
    a[mi][1] = *(const short8*)(const void*)&As[r * 72 + quad * 8 + 32];
  }
  #pragma unroll
  for (int ni = 0; ni < 4; ++ni) {
    int r = wc * 64 + ni * 16 + lr;
    b[ni][0] = *(const short8*)(const void*)&Bs[r * 72 + quad * 8];
    b[ni][1] = *(const short8*)(const void*)&Bs[r * 72 + quad * 8 + 32];
  }
  floatx4 acc[4][4] = {};
  #pragma unroll
  for (int mi = 0; mi < 4; ++mi)
    #pragma unroll
    for (int ni = 0; ni < 4; ++ni) {
      acc[mi][ni] = __builtin_amdgcn_mfma_f32_16x16x32_bf16(a[mi][0], b[ni][0], acc[mi][ni], 0, 0, 0);
      acc[mi][ni] = __builtin_amdgcn_mfma_f32_16x16x32_bf16(a[mi][1], b[ni][1], acc[mi][ni], 0, 0, 0);
    }
  #pragma unroll
  for (int mi = 0; mi < 4; ++mi) {
    #pragma unroll
    for (int reg = 0; reg < 4; ++reg) {
      int lrow = wr * 64 + mi * 16 + quad * 4 + reg;   // C/D: row=(lane>>4)*4+reg
      float msk = dmask[lrow];
      size_t rowoff = (size_t)(R0 + lrow) * NN + C0 + wc * 64;
      #pragma unroll
      for (int ni = 0; ni < 4; ++ni) {
        float x = acc[mi][ni][reg];
        float s = 1.0f / (1.0f + __expf(-x));
        out[rowoff + ni * 16 + lr] = s * msk;          // C/D: col=lane&15
      }
    }
  }
}

extern "C" void kernel_launch(void* const* d_in, const int* in_sizes, int n_in,
                              void* d_out, int out_size, void* d_ws, size_t ws_size,
                              hipStream_t stream) {
  const float* feat = (const float*)d_in[0];
  const float* adj  = (const float*)d_in[1];
  const float* W1   = (const float*)d_in[2];
  const float* a1   = (const float*)d_in[3];
  const float* W2   = (const float*)d_in[4];
  const float* a2   = (const float*)d_in[5];
  float* out = (float*)d_out;
  float* h2_out  = out;                               // [8192,64]
  float* gen_out = out + (size_t)NN * DOUT;           // [8192,8192]
  float* att_out = gen_out + (size_t)NN * NN;         // [8192,8192]
  // Big scratch lives inside gen_out: it is only written by the FINAL kernel,
  // and all readers of these intermediates run before it (stream-ordered).
  int*   csr  = (int*)gen_out;                        // 8192*256 ints (8 MB)
  float* Wh1  = gen_out + 2097152;                    // 4 MB
  float* h1   = gen_out + 3145728;                    // 4 MB
  float* Wh2  = gen_out + 4194304;                    // 2 MB
  float* f1_1 = gen_out + 4718592;
  float* f2_1 = f1_1 + NN;
  float* f1_2 = f2_1 + NN;
  float* f2_2 = f1_2 + NN;
  int* degree = (int*)d_ws;                           // 32 KB; survives to k_genenet

  k_gemm1  <<<dim3(NN / 64),  dim3(256), 0, stream>>>(feat, W1, Wh1);
  k_fvec1  <<<dim3(NN / 4),   dim3(256), 0, stream>>>(Wh1, a1, f1_1, f2_1);
  k_att1   <<<dim3(NN),       dim3(256), 0, stream>>>(adj, f1_1, f2_1, Wh1, att_out, h1, csr, degree);
  k_gemm2  <<<dim3(NN / 128), dim3(256), 0, stream>>>(h1, W2, Wh2);
  k_fvec2  <<<dim3(NN / 4),   dim3(256), 0, stream>>>(Wh2, a2, f1_2, f2_2);
  k_att2   <<<dim3(NN),       dim3(256), 0, stream>>>(csr, degree, f1_2, f2_2, Wh2, h2_out);
  k_genenet<<<dim3(64, 64),   dim3(256), 0, stream>>>(h2_out, degree, gen_out);
}

// Round 2
// 800.707 us; speedup vs baseline: 1.0559x; 1.0559x over previous
//
#include <hip/hip_runtime.h>
#include <cstdint>
#include <cstddef>

#define NN 8192
#define DIN 256
#define DHID 128
#define DOUT 64
#define MAXDEG 256

using short8  = __attribute__((ext_vector_type(8))) short;
using floatx4 = __attribute__((ext_vector_type(4))) float;

__device__ inline unsigned short f2bf(float x) {
  union { float f; unsigned u; } c; c.f = x;
  unsigned r = (c.u + 0x7FFFu + ((c.u >> 16) & 1u)) >> 16;   // RNE
  return (unsigned short)r;
}

// ---------------- GEMM1: Wh1 = feat[8192,256] @ W1[256,128] (fp32) ----------
__global__ __launch_bounds__(256) void k_gemm1(const float* __restrict__ feat,
                                               const float* __restrict__ W1,
                                               float* __restrict__ Wh1) {
  __shared__ float Ws[64 * DHID];     // k-chunk x 128 cols (32 KB)
  __shared__ float Fs[64][65];        // 64 rows x 64 k (stride 65: conflict-free)
  const int tid = threadIdx.x;
  const int cx = tid & 31;            // cols cx*4..cx*4+3
  const int ry = tid >> 5;            // rows ry*8..ry*8+7
  const int r0 = blockIdx.x * 64;
  float acc[8][4] = {};
  for (int kc = 0; kc < DIN; kc += 64) {
    const float4* src = (const float4*)(W1 + (size_t)kc * DHID);
    float4* dst = (float4*)Ws;
    #pragma unroll
    for (int i = 0; i < 8; ++i) dst[i * 256 + tid] = src[i * 256 + tid];
    #pragma unroll
    for (int i = 0; i < 4; ++i) {
      int idx = i * 256 + tid;
      int row = idx >> 4, kq = idx & 15;
      float4 v = *(const float4*)(feat + (size_t)(r0 + row) * DIN + kc + kq * 4);
      Fs[row][kq * 4 + 0] = v.x; Fs[row][kq * 4 + 1] = v.y;
      Fs[row][kq * 4 + 2] = v.z; Fs[row][kq * 4 + 3] = v.w;
    }
    __syncthreads();
    #pragma unroll 4
    for (int k = 0; k < 64; ++k) {
      float4 w = *(const float4*)(Ws + k * DHID + cx * 4);
      #pragma unroll
      for (int r = 0; r < 8; ++r) {
        float f = Fs[ry * 8 + r][k];
        acc[r][0] += f * w.x; acc[r][1] += f * w.y;
        acc[r][2] += f * w.z; acc[r][3] += f * w.w;
      }
    }
    __syncthreads();
  }
  #pragma unroll
  for (int r = 0; r < 8; ++r) {
    float4 o = make_float4(acc[r][0], acc[r][1], acc[r][2], acc[r][3]);
    *(float4*)(Wh1 + (size_t)(r0 + ry * 8 + r) * DHID + cx * 4) = o;
  }
}

// ---------------- GEMM2: Wh2 = h1[8192,128] @ W2[128,64] (fp32) -------------
__global__ __launch_bounds__(256) void k_gemm2(const float* __restrict__ h1,
                                               const float* __restrict__ W2,
                                               float* __restrict__ Wh2) {
  __shared__ float Ws[64 * DOUT];     // 16 KB
  __shared__ float Fs[128][65];       // 33 KB
  const int tid = threadIdx.x;
  const int cx = tid & 15;            // cols cx*4
  const int ry = tid >> 4;            // rows ry*8 (0..15 -> 128 rows)
  const int r0 = blockIdx.x * 128;
  float acc[8][4] = {};
  for (int kc = 0; kc < DHID; kc += 64) {
    const float4* src = (const float4*)(W2 + (size_t)kc * DOUT);
    float4* dst = (float4*)Ws;
    #pragma unroll
    for (int i = 0; i < 4; ++i) dst[i * 256 + tid] = src[i * 256 + tid];
    #pragma unroll
    for (int i = 0; i < 8; ++i) {
      int idx = i * 256 + tid;
      int row = idx >> 4, kq = idx & 15;
      float4 v = *(const float4*)(h1 + (size_t)(r0 + row) * DHID + kc + kq * 4);
      Fs[row][kq * 4 + 0] = v.x; Fs[row][kq * 4 + 1] = v.y;
      Fs[row][kq * 4 + 2] = v.z; Fs[row][kq * 4 + 3] = v.w;
    }
    __syncthreads();
    #pragma unroll 4
    for (int k = 0; k < 64; ++k) {
      float4 w = *(const float4*)(Ws + k * DOUT + cx * 4);
      #pragma unroll
      for (int r = 0; r < 8; ++r) {
        float f = Fs[ry * 8 + r][k];
        acc[r][0] += f * w.x; acc[r][1] += f * w.y;
        acc[r][2] += f * w.z; acc[r][3] += f * w.w;
      }
    }
    __syncthreads();
  }
  #pragma unroll
  for (int r = 0; r < 8; ++r) {
    float4 o = make_float4(acc[r][0], acc[r][1], acc[r][2], acc[r][3]);
    *(float4*)(Wh2 + (size_t)(r0 + ry * 8 + r) * DOUT + cx * 4) = o;
  }
}

// ---------------- f1/f2 vectors ---------------------------------------------
__global__ __launch_bounds__(256) void k_fvec1(const float* __restrict__ Wh1,
                                               const float* __restrict__ a1,
                                               float* __restrict__ f1, float* __restrict__ f2) {
  int wv = threadIdx.x >> 6, lane = threadIdx.x & 63;
  int row = blockIdx.x * 4 + wv;
  float2 x = *(const float2*)(Wh1 + (size_t)row * DHID + lane * 2);
  float2 u = *(const float2*)(a1 + lane * 2);
  float2 v = *(const float2*)(a1 + DHID + lane * 2);
  float s1 = x.x * u.x + x.y * u.y;
  float s2 = x.x * v.x + x.y * v.y;
  #pragma unroll
  for (int off = 32; off; off >>= 1) { s1 += __shfl_down(s1, off); s2 += __shfl_down(s2, off); }
  if (lane == 0) { f1[row] = s1; f2[row] = s2; }
}

__global__ __launch_bounds__(256) void k_fvec2(const float* __restrict__ Wh2,
                                               const float* __restrict__ a2,
                                               float* __restrict__ f1, float* __restrict__ f2) {
  int wv = threadIdx.x >> 6, lane = threadIdx.x & 63;
  int row = blockIdx.x * 4 + wv;
  float x = Wh2[(size_t)row * DOUT + lane];
  float s1 = x * a2[lane];
  float s2 = x * a2[DOUT + lane];
  #pragma unroll
  for (int off = 32; off; off >>= 1) { s1 += __shfl_down(s1, off); s2 += __shfl_down(s2, off); }
  if (lane == 0) { f1[row] = s1; f2[row] = s2; }
}

// ---------------- Layer-1 attention -----------------------------------------
// One block per row. deg <= 256 (expected ~82), so exactly one softmax element
// per thread: wave shfl reductions + one 4-elem LDS combine, ~6 barriers total.
__global__ __launch_bounds__(256) void k_att1(const float* __restrict__ adj,
                                              const float* __restrict__ f1v,
                                              const float* __restrict__ f2v,
                                              const float* __restrict__ Wh1,
                                              float* __restrict__ att_out,
                                              float* __restrict__ h1,
                                              int* __restrict__ csr,
                                              int* __restrict__ degree) {
  __shared__ int    scols[MAXDEG];
  __shared__ float  sval[MAXDEG];
  __shared__ float  xred[8];
  __shared__ float2 red2[256];
  __shared__ int    cnt;
  const int tid = threadIdx.x;
  const int row = blockIdx.x;
  const int wv = tid >> 6, lane = tid & 63;
  if (tid == 0) cnt = 0;
  __syncthreads();
  // Phase A: scan adjacency row (all 8 loads issued up front)
  const float4* arow = (const float4*)(adj + (size_t)row * NN);
  float4 v[8];
  #pragma unroll
  for (int it = 0; it < 8; ++it) v[it] = arow[it * 256 + tid];
  #pragma unroll
  for (int it = 0; it < 8; ++it) {
    int base4 = (it * 256 + tid) * 4;
    if (v[it].x > 0.0f) { int s = atomicAdd(&cnt, 1); if (s < MAXDEG) scols[s] = base4; }
    if (v[it].y > 0.0f) { int s = atomicAdd(&cnt, 1); if (s < MAXDEG) scols[s] = base4 + 1; }
    if (v[it].z > 0.0f) { int s = atomicAdd(&cnt, 1); if (s < MAXDEG) scols[s] = base4 + 2; }
    if (v[it].w > 0.0f) { int s = atomicAdd(&cnt, 1); if (s < MAXDEG) scols[s] = base4 + 3; }
  }
  __syncthreads();
  const int deg = min(cnt, MAXDEG);
  if (tid == 0) degree[row] = deg;
  // Phase B: e + softmax (one element per thread)
  int col = -1; float e = -3.0e38f;
  if (tid < deg) {
    col = scols[tid];
    csr[(size_t)row * MAXDEG + tid] = col;
    float t = f1v[row] + f2v[col];
    e = t > 0.0f ? t : 0.2f * t;
  }
  float m = e;
  #pragma unroll
  for (int off = 32; off; off >>= 1) m = fmaxf(m, __shfl_xor(m, off));
  if (lane == 0) xred[wv] = m;
  __syncthreads();
  m = fmaxf(fmaxf(xred[0], xred[1]), fmaxf(xred[2], xred[3]));
  float ex = (tid < deg) ? __expf(e - m) : 0.0f;
  float sm = ex;
  #pragma unroll
  for (int off = 32; off; off >>= 1) sm += __shfl_xor(sm, off);
  if (lane == 0) xred[4 + wv] = sm;
  __syncthreads();
  const float inv = 1.0f / (xred[4] + xred[5] + xred[6] + xred[7]);
  const float p = ex * inv;
  if (tid < deg) sval[tid] = p;
  // Phase C: dense attention row fill (0, or uniform 1/N if isolated)
  const float fill = (deg == 0) ? (1.0f / (float)NN) : 0.0f;
  float4 fv = make_float4(fill, fill, fill, fill);
  float4* orow = (float4*)(att_out + (size_t)row * NN);
  #pragma unroll
  for (int it = 0; it < 8; ++it) orow[it * 256 + tid] = fv;
  __syncthreads();  // drains fill stores (vmcnt) before scatter; publishes sval
  // Phase D: scatter (thread-local value, no LDS round-trip)
  if (tid < deg) att_out[(size_t)row * NN + col] = p;
  // Phase E: hp = att_row @ Wh1 (sparse), ELU -> h1. 4 groups x 64 lanes, float2.
  const int g = tid >> 6;
  float2 acc = make_float2(0.0f, 0.0f);
  if (deg > 0) {
    for (int t = g; t < deg; t += 4) {
      float sv = sval[t];
      float2 w = *(const float2*)(Wh1 + (size_t)scols[t] * DHID + lane * 2);
      acc.x += sv * w.x; acc.y += sv * w.y;
    }
  } else {
    for (int r = g; r < NN; r += 4) {
      float2 w = *(const float2*)(Wh1 + (size_t)r * DHID + lane * 2);
      acc.x += w.x; acc.y += w.y;
    }
    acc.x *= (1.0f / (float)NN); acc.y *= (1.0f / (float)NN);
  }
  red2[tid] = acc;
  __syncthreads();
  if (tid < 64) {
    float2 a0 = red2[tid], a1 = red2[tid + 64], a2 = red2[tid + 128], a3 = red2[tid + 192];
    float hx = a0.x + a1.x + a2.x + a3.x;
    float hy = a0.y + a1.y + a2.y + a3.y;
    hx = hx > 0.0f ? hx : (__expf(hx) - 1.0f);
    hy = hy > 0.0f ? hy : (__expf(hy) - 1.0f);
    *(float2*)(h1 + (size_t)row * DHID + tid * 2) = make_float2(hx, hy);
  }
}

// ---------------- Layer-2 attention (reuses CSR) ----------------------------
__global__ __launch_bounds__(256) void k_att2(const int* __restrict__ csr,
                                              const int* __restrict__ degree,
                                              const float* __restrict__ f1v,
                                              const float* __restrict__ f2v,
                                              const float* __restrict__ Wh2,
                                              float* __restrict__ h2) {
  __shared__ int   scols[MAXDEG];
  __shared__ float sval[MAXDEG];
  __shared__ float xred[8];
  __shared__ float red[256];
  const int tid = threadIdx.x;
  const int row = blockIdx.x;
  const int wv = tid >> 6, lane = tid & 63;
  const int deg = degree[row];
  int col = -1; float e = -3.0e38f;
  if (tid < deg) {
    col = csr[(size_t)row * MAXDEG + tid];
    scols[tid] = col;
    float t = f1v[row] + f2v[col];
    e = t > 0.0f ? t : 0.2f * t;
  }
  float m = e;
  #pragma unroll
  for (int off = 32; off; off >>= 1) m = fmaxf(m, __shfl_xor(m, off));
  if (lane == 0) xred[wv] = m;
  __syncthreads();
  m = fmaxf(fmaxf(xred[0], xred[1]), fmaxf(xred[2], xred[3]));
  float ex = (tid < deg) ? __expf(e - m) : 0.0f;
  float sm = ex;
  #pragma unroll
  for (int off = 32; off; off >>= 1) sm += __shfl_xor(sm, off);
  if (lane == 0) xred[4 + wv] = sm;
  __syncthreads();
  const float inv = 1.0f / (xred[4] + xred[5] + xred[6] + xred[7]);
  if (tid < deg) sval[tid] = ex * inv;
  __syncthreads();
  const int g = tid >> 6;
  float acc = 0.0f;
  if (deg > 0) {
    for (int t = g; t < deg; t += 4) acc += sval[t] * Wh2[(size_t)scols[t] * DOUT + lane];
  } else {
    for (int r = g; r < NN; r += 4) acc += Wh2[(size_t)r * DOUT + lane];
    acc *= (1.0f / (float)NN);
  }
  red[tid] = acc;
  __syncthreads();
  if (tid < 64) h2[(size_t)row * DOUT + tid] = red[tid] + red[tid + 64] + red[tid + 128] + red[tid + 192];
}

// ---------------- genenet: sigmoid(h2 @ h2^T) * rowmask (bf16 MFMA) ---------
// LDS layout: 16-B chunk c (0..7) of row r stored at slot (c+r)&7 -> bank
// stride becomes 2-way (free) instead of 8-way (2.94x) on ds_read_b128.
__global__ __launch_bounds__(256) void k_genenet(const float* __restrict__ h2,
                                                 const int* __restrict__ degree,
                                                 float* __restrict__ out) {
  __shared__ unsigned short As[128 * 64];   // 16 KB, swizzled
  __shared__ unsigned short Bs[128 * 64];
  __shared__ float dmask[128];
  const int tid = threadIdx.x;
  const int R0 = blockIdx.x * 128, C0 = blockIdx.y * 128;
  #pragma unroll
  for (int it = 0; it < 8; ++it) {
    int idx = it * 256 + tid;
    int r = idx >> 4, kq = idx & 15;
    int c = kq >> 1, hf = kq & 1;
    int off = r * 64 + (((c + r) & 7) << 3) + (hf << 2);   // in shorts, 8B-aligned
    float4 va = *(const float4*)(h2 + (size_t)(R0 + r) * DOUT + kq * 4);
    float4 vb = *(const float4*)(h2 + (size_t)(C0 + r) * DOUT + kq * 4);
    ushort4 ba = make_ushort4(f2bf(va.x), f2bf(va.y), f2bf(va.z), f2bf(va.w));
    ushort4 bb = make_ushort4(f2bf(vb.x), f2bf(vb.y), f2bf(vb.z), f2bf(vb.w));
    *(ushort4*)&As[off] = ba;
    *(ushort4*)&Bs[off] = bb;
  }
  if (tid < 128) dmask[tid] = (degree[R0 + tid] > 0) ? 1.0f : 0.0f;
  __syncthreads();
  const int wave = tid >> 6, lane = tid & 63;
  const int wr = wave >> 1, wc = wave & 1;     // 2x2 waves over 128x128 tile
  const int lr = lane & 15, quad = lane >> 4;
  short8 a[4][2], b[4][2];
  #pragma unroll
  for (int mi = 0; mi < 4; ++mi) {
    int r = wr * 64 + mi * 16 + lr;
    #pragma unroll
    for (int j = 0; j < 2; ++j) {
      int c = quad + 4 * j;
      a[mi][j] = *(const short8*)(const void*)&As[r * 64 + (((c + r) & 7) << 3)];
    }
  }
  #pragma unroll
  for (int ni = 0; ni < 4; ++ni) {
    int r = wc * 64 + ni * 16 + lr;
    #pragma unroll
    for (int j = 0; j < 2; ++j) {
      int c = quad + 4 * j;
      b[ni][j] = *(const short8*)(const void*)&Bs[r * 64 + (((c + r) & 7) << 3)];
    }
  }
  floatx4 acc[4][4] = {};
  #pragma unroll
  for (int mi = 0; mi < 4; ++mi)
    #pragma unroll
    for (int ni = 0; ni < 4; ++ni) {
      acc[mi][ni] = __builtin_amdgcn_mfma_f32_16x16x32_bf16(a[mi][0], b[ni][0], acc[mi][ni], 0, 0, 0);
      acc[mi][ni] = __builtin_amdgcn_mfma_f32_16x16x32_bf16(a[mi][1], b[ni][1], acc[mi][ni], 0, 0, 0);
    }
  #pragma unroll
  for (int mi = 0; mi < 4; ++mi) {
    #pragma unroll
    for (int reg = 0; reg < 4; ++reg) {
      int lrow = wr * 64 + mi * 16 + quad * 4 + reg;   // C/D: row=(lane>>4)*4+reg
      float msk = dmask[lrow];
      size_t rowoff = (size_t)(R0 + lrow) * NN + C0 + wc * 64;
      #pragma unroll
      for (int ni = 0; ni < 4; ++ni) {
        float x = acc[mi][ni][reg];
        float s = __builtin_amdgcn_rcpf(1.0f + __expf(-x));
        out[rowoff + ni * 16 + lr] = s * msk;          // C/D: col=lane&15
      }
    }
  }
}

extern "C" void kernel_launch(void* const* d_in, const int* in_sizes, int n_in,
                              void* d_out, int out_size, void* d_ws, size_t ws_size,
                              hipStream_t stream) {
  const float* feat = (const float*)d_in[0];
  const float* adj  = (const float*)d_in[1];
  const float* W1   = (const float*)d_in[2];
  const float* a1   = (const float*)d_in[3];
  const float* W2   = (const float*)d_in[4];
  const float* a2   = (const float*)d_in[5];
  float* out = (float*)d_out;
  float* h2_out  = out;                               // [8192,64]
  float* gen_out = out + (size_t)NN * DOUT;           // [8192,8192]
  float* att_out = gen_out + (size_t)NN * NN;         // [8192,8192]
  // Big scratch lives inside gen_out: it is only written by the FINAL kernel,
  // and all readers of these intermediates run before it (stream-ordered).
  int*   csr  = (int*)gen_out;                        // 8192*256 ints (8 MB)
  float* Wh1  = gen_out + 2097152;                    // 4 MB
  float* h1   = gen_out + 3145728;                    // 4 MB
  float* Wh2  = gen_out + 4194304;                    // 2 MB
  float* f1_1 = gen_out + 4718592;
  float* f2_1 = f1_1 + NN;
  float* f1_2 = f2_1 + NN;
  float* f2_2 = f1_2 + NN;
  int* degree = (int*)d_ws;                           // 32 KB; survives to k_genenet

  k_gemm1  <<<dim3(NN / 64),  dim3(256), 0, stream>>>(feat, W1, Wh1);
  k_fvec1  <<<dim3(NN / 4),   dim3(256), 0, stream>>>(Wh1, a1, f1_1, f2_1);
  k_att1   <<<dim3(NN),       dim3(256), 0, stream>>>(adj, f1_1, f2_1, Wh1, att_out, h1, csr, degree);
  k_gemm2  <<<dim3(NN / 128), dim3(256), 0, stream>>>(h1, W2, Wh2);
  k_fvec2  <<<dim3(NN / 4),   dim3(256), 0, stream>>>(Wh2, a2, f1_2, f2_2);
  k_att2   <<<dim3(NN),       dim3(256), 0, stream>>>(csr, degree, f1_2, f2_2, Wh2, h2_out);
  k_genenet<<<dim3(64, 64),   dim3(256), 0, stream>>>(h2_out, degree, gen_out);
}